// Round 5
// baseline (398.438 us; speedup 1.0000x reference)
//
#include <hip/hip_runtime.h>
#include <hip/hip_bf16.h>
#include <math.h>

#define F_IN 128
#define F_HID 256
#define F_OUT 10

typedef __attribute__((ext_vector_type(4))) short s16x4;
typedef __attribute__((ext_vector_type(8))) short s16x8;
typedef __attribute__((ext_vector_type(4))) float f32x4;

static __device__ __forceinline__ float b2f(unsigned short u) {
    union { float f; unsigned int u; } c;
    c.u = ((unsigned int)u) << 16;
    return c.f;
}
static __device__ __forceinline__ unsigned short f2b(float f) {
    return __bfloat16_as_ushort(__float2bfloat16(f));
}

// ---------------- fused prep: degree count + bf16 casts ----------------
// blockIdx.y: 0=count, 1=cast x, 2=castT W1, 3=castT W2

__global__ void prep_kernel(const int* __restrict__ dst, int* __restrict__ cnt, int e,
                            const float* __restrict__ x, unsigned short* __restrict__ xb,
                            int xq,
                            const float* __restrict__ W1, unsigned short* __restrict__ W1t,
                            const float* __restrict__ W2, unsigned short* __restrict__ W2t) {
    int i = blockIdx.x * blockDim.x + threadIdx.x;
    int job = blockIdx.y;
    if (job == 0) {
        if (i < e) atomicAdd(&cnt[dst[i]], 1);
    } else if (job == 1) {
        if (i < xq) {
            float4 v = *(const float4*)&x[(size_t)i * 4];
            ushort4 o;
            o.x = f2b(v.x); o.y = f2b(v.y); o.z = f2b(v.z); o.w = f2b(v.w);
            *(ushort4*)&xb[(size_t)i * 4] = o;
        }
    } else if (job == 2) {
        if (i < F_IN * F_HID) {
            int k = i / F_HID, nn = i - k * F_HID;
            W1t[nn * F_IN + k] = f2b(W1[i]);
        }
    } else {
        if (i < F_HID * F_HID) {
            int k = i / F_HID, nn = i - k * F_HID;
            W2t[nn * F_HID + k] = f2b(W2[i]);
        }
    }
}

// ---------------- scan (rowstart) + dinv ----------------

__global__ void scan1_kernel(const int* __restrict__ cnt, int* __restrict__ rowstart,
                             int* __restrict__ partial, float* __restrict__ dinv, int n) {
    __shared__ int s[256];
    int tid = threadIdx.x;
    int i = blockIdx.x * 256 + tid;
    int v = (i < n) ? cnt[i] : 0;
    s[tid] = v;
    __syncthreads();
    for (int off = 1; off < 256; off <<= 1) {
        int t = (tid >= off) ? s[tid - off] : 0;
        __syncthreads();
        s[tid] += t;
        __syncthreads();
    }
    if (i < n) {
        rowstart[i] = s[tid] - v;                 // exclusive
        dinv[i] = rsqrtf((float)(v + 1));         // +1 self loop
    }
    if (tid == 255) partial[blockIdx.x] = s[255]; // block total
}

__global__ void scan2_kernel(int* __restrict__ partial, int nb) {
    __shared__ int s[256];
    int tid = threadIdx.x;
    int v = (tid < nb) ? partial[tid] : 0;
    s[tid] = v;
    __syncthreads();
    for (int off = 1; off < 256; off <<= 1) {
        int t = (tid >= off) ? s[tid - off] : 0;
        __syncthreads();
        s[tid] += t;
        __syncthreads();
    }
    if (tid < nb) partial[tid] = s[tid] - v;      // exclusive block offsets
}

__global__ void scan3_kernel(int* __restrict__ rowstart, const int* __restrict__ partial,
                             int n, int e) {
    int i = blockIdx.x * blockDim.x + threadIdx.x;
    if (i < n) rowstart[i] += partial[blockIdx.x];
    if (i == 0) rowstart[n] = e;
}

__global__ void fill_kernel(const int* __restrict__ src, const int* __restrict__ dst,
                            const int* __restrict__ rowstart, int* __restrict__ cursor,
                            const float* __restrict__ dinv, int2* __restrict__ pack, int e) {
    int i = blockIdx.x * blockDim.x + threadIdx.x;
    if (i >= e) return;
    int s = src[i], d = dst[i];
    int pos = rowstart[d] + atomicAdd(&cursor[d], 1);
    float w = dinv[s] * dinv[d];
    pack[pos] = make_int2(s, __float_as_int(w));
}

// ---------------- feature-sliced aggregation ----------------
// Pass p (blockIdx.y) handles feats [p*32, p*32+32): table slice 3.2 MB -> L2-resident.
// Wave per node: 16 lanes (fidx, ushort2 each) x 4 edge-subgroups; shfl_xor reduce.

template <int F>
__global__ __launch_bounds__(256) void agg_split_kernel(const unsigned short* __restrict__ feat,
                                                        const int* __restrict__ rowstart,
                                                        const int2* __restrict__ pack,
                                                        const float* __restrict__ dinv,
                                                        unsigned short* __restrict__ out,
                                                        int n) {
    int wid = threadIdx.x >> 6;
    int lane = threadIdx.x & 63;
    int v = blockIdx.x * 4 + wid;
    if (v >= n) return;
    int esub = lane >> 4;      // 0..3
    int fidx = lane & 15;      // 0..15
    int fbase = blockIdx.y * 32;
    const unsigned short* fcol = feat + fbase + fidx * 2;

    float d = dinv[v];
    float sw = (esub == 0) ? d * d : 0.f;
    float a0, a1;
    {
        ushort2 t = *(const ushort2*)&fcol[(size_t)v * F];
        a0 = sw * b2f(t.x);
        a1 = sw * b2f(t.y);
    }

    int e0 = rowstart[v], e1 = rowstart[v + 1];
    for (int e = e0; e < e1; e += 8) {
        int ea = e + esub;
        int eb = e + 4 + esub;
        bool oka = ea < e1;
        bool okb = eb < e1;
        int2 pa = pack[oka ? ea : e];
        int2 pb = pack[okb ? eb : e];
        float wa = oka ? __int_as_float(pa.y) : 0.f;
        float wb = okb ? __int_as_float(pb.y) : 0.f;
        ushort2 ta = *(const ushort2*)&fcol[(size_t)pa.x * F];
        ushort2 tb = *(const ushort2*)&fcol[(size_t)pb.x * F];
        a0 += wa * b2f(ta.x);
        a1 += wa * b2f(ta.y);
        a0 += wb * b2f(tb.x);
        a1 += wb * b2f(tb.y);
    }

    // sum over esub groups: xor 16 then xor 32
    a0 += __shfl_xor(a0, 16);
    a1 += __shfl_xor(a1, 16);
    a0 += __shfl_xor(a0, 32);
    a1 += __shfl_xor(a1, 32);

    if (esub == 0) {
        ushort2 o;
        o.x = f2b(a0);
        o.y = f2b(a1);
        *(ushort2*)&out[(size_t)v * F + fbase + fidx * 2] = o;
    }
}

// ---------------- MFMA bf16 GEMM: C[M,N] = A[M,K]bf16 @ Wt[N,K]bf16^T (+bias, relu) ------

template <int K, bool RELU, bool BF16OUT>
__global__ __launch_bounds__(256) void gemm_mfma_kernel(const unsigned short* __restrict__ A,
                                                        const unsigned short* __restrict__ Bt,
                                                        const float* __restrict__ bias,
                                                        float* __restrict__ C,
                                                        unsigned short* __restrict__ Cb,
                                                        int M, int N) {
    __shared__ unsigned short As[64][40];  // 80B row stride: 16B-aligned, 2-way-max banks
    __shared__ unsigned short Bs[64][40];  // Bs[col][k]
    int tid = threadIdx.x;
    int w = tid >> 6;
    int lane = tid & 63;
    int g = lane >> 4;     // k-group
    int r16 = lane & 15;
    int bm = blockIdx.x, bn = blockIdx.y;

    int srow = tid >> 2;        // staging row 0..63
    int scol = (tid & 3) * 8;   // staging col 0,8,16,24
    int garow = bm * 64 + srow;
    int gbrow = bn * 64 + srow;

    f32x4 acc[4] = {};

    for (int k0 = 0; k0 < K; k0 += 32) {
        uint4 av = make_uint4(0, 0, 0, 0);
        if (garow < M) av = *(const uint4*)&A[(size_t)garow * K + k0 + scol];
        uint4 bv = *(const uint4*)&Bt[(size_t)gbrow * K + k0 + scol];
        __syncthreads();  // protect previous iteration's LDS reads
        *(uint4*)&As[srow][scol] = av;
        *(uint4*)&Bs[srow][scol] = bv;
        __syncthreads();

        union U { s16x8 v; s16x4 h[2]; };
        U af;
        int arow = w * 16 + r16;
        af.h[0] = *(const s16x4*)&As[arow][g * 4];
        af.h[1] = *(const s16x4*)&As[arow][g * 4 + 16];
#pragma unroll
        for (int cg = 0; cg < 4; ++cg) {
            U bf;
            bf.h[0] = *(const s16x4*)&Bs[cg * 16 + r16][g * 4];
            bf.h[1] = *(const s16x4*)&Bs[cg * 16 + r16][g * 4 + 16];
            acc[cg] = __builtin_amdgcn_mfma_f32_16x16x32_bf16(af.v, bf.v, acc[cg], 0, 0, 0);
        }
    }

    // epilogue: C/D layout col=lane&15, row=(lane>>4)*4+reg
#pragma unroll
    for (int cg = 0; cg < 4; ++cg) {
        int col = bn * 64 + cg * 16 + r16;
        float bs = bias[col];
#pragma unroll
        for (int r = 0; r < 4; ++r) {
            int row = bm * 64 + w * 16 + g * 4 + r;
            if (row < M) {
                float v = acc[cg][r] + bs;
                if (RELU) v = fmaxf(v, 0.f);
                if (BF16OUT) {
                    Cb[(size_t)row * N + col] = f2b(v);
                } else {
                    C[(size_t)row * N + col] = v;
                }
            }
        }
    }
}

// ---------------- small GEMM: hw3[M,10] = h[M,256] @ W3[256,10] ----------------

__global__ void gemm3_kernel(const float* __restrict__ h, const float* __restrict__ W3,
                             float* __restrict__ hw3, int M) {
    __shared__ float w[F_HID * F_OUT];
    for (int i = threadIdx.x; i < F_HID * F_OUT; i += blockDim.x) w[i] = W3[i];
    __syncthreads();
    int r = blockIdx.x * blockDim.x + threadIdx.x;
    if (r >= M) return;
    float acc[F_OUT] = {};
    const float* row = &h[(size_t)r * F_HID];
    for (int k = 0; k < F_HID; k += 4) {
        float4 hv = *(const float4*)&row[k];
#pragma unroll
        for (int j = 0; j < F_OUT; ++j) {
            acc[j] += hv.x * w[(k + 0) * F_OUT + j];
            acc[j] += hv.y * w[(k + 1) * F_OUT + j];
            acc[j] += hv.z * w[(k + 2) * F_OUT + j];
            acc[j] += hv.w * w[(k + 3) * F_OUT + j];
        }
    }
#pragma unroll
    for (int j = 0; j < F_OUT; ++j) hw3[(size_t)r * F_OUT + j] = acc[j];
}

// ---------------- final: 10-dim aggregation + bias + log_softmax ----------------

__global__ void final_kernel(const float* __restrict__ hw3, const int* __restrict__ rowstart,
                             const int2* __restrict__ pack, const float* __restrict__ dinv,
                             const float* __restrict__ b3, float* __restrict__ out, int n) {
    int v = blockIdx.x * blockDim.x + threadIdx.x;
    if (v >= n) return;
    float acc[F_OUT];
    float d = dinv[v];
    float sw = d * d;
#pragma unroll
    for (int j = 0; j < F_OUT; ++j) acc[j] = sw * hw3[(size_t)v * F_OUT + j];
    int e0 = rowstart[v], e1 = rowstart[v + 1];
    for (int e = e0; e < e1; ++e) {
        int2 p = pack[e];
        float w = __int_as_float(p.y);
#pragma unroll
        for (int j = 0; j < F_OUT; ++j) acc[j] += w * hw3[(size_t)p.x * F_OUT + j];
    }
#pragma unroll
    for (int j = 0; j < F_OUT; ++j) acc[j] += b3[j];
    float m = acc[0];
#pragma unroll
    for (int j = 1; j < F_OUT; ++j) m = fmaxf(m, acc[j]);
    float sum = 0.f;
#pragma unroll
    for (int j = 0; j < F_OUT; ++j) sum += expf(acc[j] - m);
    float lse = m + logf(sum);
#pragma unroll
    for (int j = 0; j < F_OUT; ++j) out[(size_t)v * F_OUT + j] = acc[j] - lse;
}

// ---------------- launch ----------------

extern "C" void kernel_launch(void* const* d_in, const int* in_sizes, int n_in,
                              void* d_out, int out_size, void* d_ws, size_t ws_size,
                              hipStream_t stream) {
    const float* x  = (const float*)d_in[0];
    const int*   ei = (const int*)d_in[1];
    const float* W1 = (const float*)d_in[2];
    const float* b1 = (const float*)d_in[3];
    const float* W2 = (const float*)d_in[4];
    const float* b2 = (const float*)d_in[5];
    const float* W3 = (const float*)d_in[6];
    const float* b3 = (const float*)d_in[7];
    float* out = (float*)d_out;

    int n = in_sizes[0] / F_IN;
    int e = in_sizes[1] / 2;
    const int* srcp = ei;
    const int* dstp = ei + e;

    size_t off = 0;
    auto alloc = [&](size_t bytes) -> char* {
        char* p = (char*)d_ws + off;
        off += (bytes + 255) & ~(size_t)255;
        return p;
    };
    size_t cntpad = ((size_t)n * 4 + 255) & ~(size_t)255;
    int*   cnt      = (int*)alloc((size_t)n * 4);
    int*   cursor   = (int*)alloc((size_t)n * 4);   // adjacent to cnt: single memset
    int*   rowstart = (int*)alloc((size_t)(n + 1) * 4);
    int*   partial  = (int*)alloc(1024 * 4);
    int2*  pack     = (int2*)alloc((size_t)e * 8);
    float* dinv     = (float*)alloc((size_t)n * 4);
    unsigned short* xb   = (unsigned short*)alloc((size_t)n * F_IN * 2);   // x bf16
    unsigned short* aggb = (unsigned short*)alloc((size_t)n * F_HID * 2);  // agg out bf16
    unsigned short* h1b  = (unsigned short*)alloc((size_t)n * F_HID * 2);  // h1 bf16
    unsigned short* W1t  = (unsigned short*)alloc((size_t)F_IN * F_HID * 2);
    unsigned short* W2t  = (unsigned short*)alloc((size_t)F_HID * F_HID * 2);
    float* h2  = (float*)alloc((size_t)n * F_HID * 4);
    float* hw3 = (float*)alloc((size_t)n * F_OUT * 4);

    const int TB = 256;
    // one memset covers cnt + cursor (adjacent)
    hipMemsetAsync(cnt, 0, cntpad + (size_t)n * 4, stream);

    // prep: count + cast x + castT W1 + castT W2
    int xq = (int)((size_t)n * F_IN / 4);
    int prepmax = e > xq ? e : xq;
    dim3 gp((prepmax + TB - 1) / TB, 4);
    prep_kernel<<<gp, TB, 0, stream>>>(dstp, cnt, e, x, xb, xq, W1, W1t, W2, W2t);

    int nb = (n + TB - 1) / TB;
    scan1_kernel<<<nb, TB, 0, stream>>>(cnt, rowstart, partial, dinv, n);
    scan2_kernel<<<1, TB, 0, stream>>>(partial, nb);
    scan3_kernel<<<nb, TB, 0, stream>>>(rowstart, partial, n, e);
    fill_kernel<<<(e + TB - 1) / TB, TB, 0, stream>>>(srcp, dstp, rowstart, cursor, dinv,
                                                      pack, e);

    int nwave = (n + 3) / 4;
    dim3 gg((n + 63) / 64, F_HID / 64);
    dim3 ga1(nwave, F_IN / 32);
    dim3 ga2(nwave, F_HID / 32);

    // Layer 1: sliced-agg x_bf16 (128) -> aggb, MFMA GEMM+bias+relu -> h1 (bf16)
    agg_split_kernel<F_IN><<<ga1, 256, 0, stream>>>(xb, rowstart, pack, dinv, aggb, n);
    gemm_mfma_kernel<F_IN, true, true><<<gg, 256, 0, stream>>>(aggb, W1t, b1, nullptr, h1b,
                                                               n, F_HID);

    // Layer 2: sliced-agg h1_bf16 (256) -> aggb, MFMA GEMM+bias+relu -> h2 (fp32)
    agg_split_kernel<F_HID><<<ga2, 256, 0, stream>>>(h1b, rowstart, pack, dinv, aggb, n);
    gemm_mfma_kernel<F_HID, true, false><<<gg, 256, 0, stream>>>(aggb, W2t, b2, h2, nullptr,
                                                                 n, F_HID);

    // Layer 3: GEMM to 10-dim, aggregate 10-dim + bias + log_softmax
    gemm3_kernel<<<(n + TB - 1) / TB, TB, 0, stream>>>(h2, W3, hw3, n);
    final_kernel<<<(n + TB - 1) / TB, TB, 0, stream>>>(hw3, rowstart, pack, dinv, b3, out, n);
}

// Round 6
// 269.011 us; speedup vs baseline: 1.4811x; 1.4811x over previous
//
#include <hip/hip_runtime.h>
#include <hip/hip_bf16.h>
#include <math.h>

#define F_IN 128
#define F_HID 256
#define F_OUT 10

typedef __attribute__((ext_vector_type(4))) short s16x4;
typedef __attribute__((ext_vector_type(8))) short s16x8;
typedef __attribute__((ext_vector_type(4))) float f32x4;

static __device__ __forceinline__ float b2f(unsigned short u) {
    union { float f; unsigned int u; } c;
    c.u = ((unsigned int)u) << 16;
    return c.f;
}
static __device__ __forceinline__ unsigned short f2b(float f) {
    return __bfloat16_as_ushort(__float2bfloat16(f));
}

// ---------------- fused prep: degree count + bf16 casts ----------------
// blockIdx.y: 0=count, 1=cast x, 2=castT W1, 3=castT W2

__global__ void prep_kernel(const int* __restrict__ dst, int* __restrict__ cnt, int e,
                            const float* __restrict__ x, unsigned short* __restrict__ xb,
                            int xq,
                            const float* __restrict__ W1, unsigned short* __restrict__ W1t,
                            const float* __restrict__ W2, unsigned short* __restrict__ W2t) {
    int i = blockIdx.x * blockDim.x + threadIdx.x;
    int job = blockIdx.y;
    if (job == 0) {
        if (i < e) atomicAdd(&cnt[dst[i]], 1);
    } else if (job == 1) {
        if (i < xq) {
            float4 v = *(const float4*)&x[(size_t)i * 4];
            ushort4 o;
            o.x = f2b(v.x); o.y = f2b(v.y); o.z = f2b(v.z); o.w = f2b(v.w);
            *(ushort4*)&xb[(size_t)i * 4] = o;
        }
    } else if (job == 2) {
        if (i < F_IN * F_HID) {
            int k = i / F_HID, nn = i - k * F_HID;
            W1t[nn * F_IN + k] = f2b(W1[i]);
        }
    } else {
        if (i < F_HID * F_HID) {
            int k = i / F_HID, nn = i - k * F_HID;
            W2t[nn * F_HID + k] = f2b(W2[i]);
        }
    }
}

// ---------------- scan (rowstart) + dinv ----------------

__global__ void scan1_kernel(const int* __restrict__ cnt, int* __restrict__ rowstart,
                             int* __restrict__ partial, float* __restrict__ dinv, int n) {
    __shared__ int s[256];
    int tid = threadIdx.x;
    int i = blockIdx.x * 256 + tid;
    int v = (i < n) ? cnt[i] : 0;
    s[tid] = v;
    __syncthreads();
    for (int off = 1; off < 256; off <<= 1) {
        int t = (tid >= off) ? s[tid - off] : 0;
        __syncthreads();
        s[tid] += t;
        __syncthreads();
    }
    if (i < n) {
        rowstart[i] = s[tid] - v;                 // exclusive
        dinv[i] = rsqrtf((float)(v + 1));         // +1 self loop
    }
    if (tid == 255) partial[blockIdx.x] = s[255]; // block total
}

__global__ void scan2_kernel(int* __restrict__ partial, int nb) {
    __shared__ int s[256];
    int tid = threadIdx.x;
    int v = (tid < nb) ? partial[tid] : 0;
    s[tid] = v;
    __syncthreads();
    for (int off = 1; off < 256; off <<= 1) {
        int t = (tid >= off) ? s[tid - off] : 0;
        __syncthreads();
        s[tid] += t;
        __syncthreads();
    }
    if (tid < nb) partial[tid] = s[tid] - v;      // exclusive block offsets
}

__global__ void scan3_kernel(int* __restrict__ rowstart, const int* __restrict__ partial,
                             int n, int e) {
    int i = blockIdx.x * blockDim.x + threadIdx.x;
    if (i < n) rowstart[i] += partial[blockIdx.x];
    if (i == 0) rowstart[n] = e;
}

__global__ void fill_kernel(const int* __restrict__ src, const int* __restrict__ dst,
                            const int* __restrict__ rowstart, int* __restrict__ cursor,
                            const float* __restrict__ dinv, int2* __restrict__ pack, int e) {
    int i = blockIdx.x * blockDim.x + threadIdx.x;
    if (i >= e) return;
    int s = src[i], d = dst[i];
    int pos = rowstart[d] + atomicAdd(&cursor[d], 1);
    float w = dinv[s] * dinv[d];
    pack[pos] = make_int2(s, __float_as_int(w));
}

// ---------------- aggregation: wave per node, 16B/lane, edge-group parallel ----------------
// F=256: 32 lanes/row (s16x8 each) x 2 edge-groups; F=128: 16 lanes/row x 4 groups.
// Unroll 4 per group -> 8/16 full-row gathers in flight per wave. shfl_xor group reduce.

template <int F>
__global__ __launch_bounds__(256) void agg_kernel(const unsigned short* __restrict__ feat,
                                                  const int* __restrict__ rowstart,
                                                  const int2* __restrict__ pack,
                                                  const float* __restrict__ dinv,
                                                  unsigned short* __restrict__ out, int n) {
    constexpr int LPF = F / 8;       // lanes per feature row
    constexpr int EG = 64 / LPF;     // edge groups per wave
    int wid = threadIdx.x >> 6;
    int lane = threadIdx.x & 63;
    int v = blockIdx.x * 4 + wid;
    if (v >= n) return;
    int eg = lane / LPF;
    int fl = lane % LPF;
    const unsigned short* fp = feat + fl * 8;

    float acc[8];
    {
        float d = dinv[v];
        float sw = (eg == 0) ? d * d : 0.f;
        s16x8 t = *(const s16x8*)&fp[(size_t)v * F];
#pragma unroll
        for (int j = 0; j < 8; ++j) acc[j] = sw * b2f((unsigned short)t[j]);
    }

    int e0 = rowstart[v], e1 = rowstart[v + 1];
    constexpr int STEP = EG * 4;
    int e = e0;
    for (; e + STEP <= e1; e += STEP) {
        int2 p[4];
#pragma unroll
        for (int u = 0; u < 4; ++u) p[u] = pack[e + eg + u * EG];
        s16x8 t[4];
#pragma unroll
        for (int u = 0; u < 4; ++u) t[u] = *(const s16x8*)&fp[(size_t)p[u].x * F];
#pragma unroll
        for (int u = 0; u < 4; ++u) {
            float w = __int_as_float(p[u].y);
#pragma unroll
            for (int j = 0; j < 8; ++j) acc[j] += w * b2f((unsigned short)t[u][j]);
        }
    }
    for (int ee = e + eg; ee < e1; ee += EG) {
        int2 p = pack[ee];
        float w = __int_as_float(p.y);
        s16x8 t = *(const s16x8*)&fp[(size_t)p.x * F];
#pragma unroll
        for (int j = 0; j < 8; ++j) acc[j] += w * b2f((unsigned short)t[j]);
    }

    // reduce across edge groups
    if (EG == 4) {
#pragma unroll
        for (int j = 0; j < 8; ++j) acc[j] += __shfl_xor(acc[j], 16);
    }
#pragma unroll
    for (int j = 0; j < 8; ++j) acc[j] += __shfl_xor(acc[j], 32);

    if (eg == 0) {
        s16x8 o;
#pragma unroll
        for (int j = 0; j < 8; ++j) o[j] = (short)f2b(acc[j]);
        *(s16x8*)&out[(size_t)v * F + fl * 8] = o;
    }
}

// ---------------- MFMA bf16 GEMM: C[M,N] = A[M,K]bf16 @ Wt[N,K]bf16^T (+bias, relu) ------

template <int K, bool RELU, bool BF16OUT>
__global__ __launch_bounds__(256) void gemm_mfma_kernel(const unsigned short* __restrict__ A,
                                                        const unsigned short* __restrict__ Bt,
                                                        const float* __restrict__ bias,
                                                        float* __restrict__ C,
                                                        unsigned short* __restrict__ Cb,
                                                        int M, int N) {
    __shared__ unsigned short As[64][40];  // 80B row stride: 16B-aligned, 2-way-max banks
    __shared__ unsigned short Bs[64][40];  // Bs[col][k]
    int tid = threadIdx.x;
    int w = tid >> 6;
    int lane = tid & 63;
    int g = lane >> 4;     // k-group
    int r16 = lane & 15;
    int bm = blockIdx.x, bn = blockIdx.y;

    int srow = tid >> 2;        // staging row 0..63
    int scol = (tid & 3) * 8;   // staging col 0,8,16,24
    int garow = bm * 64 + srow;
    int gbrow = bn * 64 + srow;

    f32x4 acc[4] = {};

    for (int k0 = 0; k0 < K; k0 += 32) {
        uint4 av = make_uint4(0, 0, 0, 0);
        if (garow < M) av = *(const uint4*)&A[(size_t)garow * K + k0 + scol];
        uint4 bv = *(const uint4*)&Bt[(size_t)gbrow * K + k0 + scol];
        __syncthreads();  // protect previous iteration's LDS reads
        *(uint4*)&As[srow][scol] = av;
        *(uint4*)&Bs[srow][scol] = bv;
        __syncthreads();

        union U { s16x8 v; s16x4 h[2]; };
        U af;
        int arow = w * 16 + r16;
        af.h[0] = *(const s16x4*)&As[arow][g * 4];
        af.h[1] = *(const s16x4*)&As[arow][g * 4 + 16];
#pragma unroll
        for (int cg = 0; cg < 4; ++cg) {
            U bf;
            bf.h[0] = *(const s16x4*)&Bs[cg * 16 + r16][g * 4];
            bf.h[1] = *(const s16x4*)&Bs[cg * 16 + r16][g * 4 + 16];
            acc[cg] = __builtin_amdgcn_mfma_f32_16x16x32_bf16(af.v, bf.v, acc[cg], 0, 0, 0);
        }
    }

    // epilogue: C/D layout col=lane&15, row=(lane>>4)*4+reg
#pragma unroll
    for (int cg = 0; cg < 4; ++cg) {
        int col = bn * 64 + cg * 16 + r16;
        float bs = bias[col];
#pragma unroll
        for (int r = 0; r < 4; ++r) {
            int row = bm * 64 + w * 16 + g * 4 + r;
            if (row < M) {
                float v = acc[cg][r] + bs;
                if (RELU) v = fmaxf(v, 0.f);
                if (BF16OUT) {
                    Cb[(size_t)row * N + col] = f2b(v);
                } else {
                    C[(size_t)row * N + col] = v;
                }
            }
        }
    }
}

// ---------------- small GEMM: hw3[M,10] = h_bf16[M,256] @ W3[256,10] ----------------

__global__ void gemm3_kernel(const unsigned short* __restrict__ h, const float* __restrict__ W3,
                             float* __restrict__ hw3, int M) {
    __shared__ float w[F_HID * F_OUT];
    for (int i = threadIdx.x; i < F_HID * F_OUT; i += blockDim.x) w[i] = W3[i];
    __syncthreads();
    int r = blockIdx.x * blockDim.x + threadIdx.x;
    if (r >= M) return;
    float acc[F_OUT] = {};
    const unsigned short* row = &h[(size_t)r * F_HID];
    for (int k = 0; k < F_HID; k += 8) {
        s16x8 hv = *(const s16x8*)&row[k];
#pragma unroll
        for (int u = 0; u < 8; ++u) {
            float hvf = b2f((unsigned short)hv[u]);
#pragma unroll
            for (int j = 0; j < F_OUT; ++j) acc[j] += hvf * w[(k + u) * F_OUT + j];
        }
    }
#pragma unroll
    for (int j = 0; j < F_OUT; ++j) hw3[(size_t)r * F_OUT + j] = acc[j];
}

// ---------------- final: 10-dim aggregation + bias + log_softmax ----------------

__global__ void final_kernel(const float* __restrict__ hw3, const int* __restrict__ rowstart,
                             const int2* __restrict__ pack, const float* __restrict__ dinv,
                             const float* __restrict__ b3, float* __restrict__ out, int n) {
    int v = blockIdx.x * blockDim.x + threadIdx.x;
    if (v >= n) return;
    float acc[F_OUT];
    float d = dinv[v];
    float sw = d * d;
#pragma unroll
    for (int j = 0; j < F_OUT; ++j) acc[j] = sw * hw3[(size_t)v * F_OUT + j];
    int e0 = rowstart[v], e1 = rowstart[v + 1];
    for (int e = e0; e < e1; ++e) {
        int2 p = pack[e];
        float w = __int_as_float(p.y);
#pragma unroll
        for (int j = 0; j < F_OUT; ++j) acc[j] += w * hw3[(size_t)p.x * F_OUT + j];
    }
#pragma unroll
    for (int j = 0; j < F_OUT; ++j) acc[j] += b3[j];
    float m = acc[0];
#pragma unroll
    for (int j = 1; j < F_OUT; ++j) m = fmaxf(m, acc[j]);
    float sum = 0.f;
#pragma unroll
    for (int j = 0; j < F_OUT; ++j) sum += expf(acc[j] - m);
    float lse = m + logf(sum);
#pragma unroll
    for (int j = 0; j < F_OUT; ++j) out[(size_t)v * F_OUT + j] = acc[j] - lse;
}

// ---------------- launch ----------------

extern "C" void kernel_launch(void* const* d_in, const int* in_sizes, int n_in,
                              void* d_out, int out_size, void* d_ws, size_t ws_size,
                              hipStream_t stream) {
    const float* x  = (const float*)d_in[0];
    const int*   ei = (const int*)d_in[1];
    const float* W1 = (const float*)d_in[2];
    const float* b1 = (const float*)d_in[3];
    const float* W2 = (const float*)d_in[4];
    const float* b2 = (const float*)d_in[5];
    const float* W3 = (const float*)d_in[6];
    const float* b3 = (const float*)d_in[7];
    float* out = (float*)d_out;

    int n = in_sizes[0] / F_IN;
    int e = in_sizes[1] / 2;
    const int* srcp = ei;
    const int* dstp = ei + e;

    size_t off = 0;
    auto alloc = [&](size_t bytes) -> char* {
        char* p = (char*)d_ws + off;
        off += (bytes + 255) & ~(size_t)255;
        return p;
    };
    size_t cntpad = ((size_t)n * 4 + 255) & ~(size_t)255;
    int*   cnt      = (int*)alloc((size_t)n * 4);
    int*   cursor   = (int*)alloc((size_t)n * 4);   // adjacent to cnt: single memset
    int*   rowstart = (int*)alloc((size_t)(n + 1) * 4);
    int*   partial  = (int*)alloc(1024 * 4);
    int2*  pack     = (int2*)alloc((size_t)e * 8);
    float* dinv     = (float*)alloc((size_t)n * 4);
    unsigned short* xb   = (unsigned short*)alloc((size_t)n * F_IN * 2);   // x bf16
    unsigned short* aggb = (unsigned short*)alloc((size_t)n * F_HID * 2);  // agg out bf16
    unsigned short* h1b  = (unsigned short*)alloc((size_t)n * F_HID * 2);  // h1 bf16
    unsigned short* h2b  = (unsigned short*)alloc((size_t)n * F_HID * 2);  // h2 bf16
    unsigned short* W1t  = (unsigned short*)alloc((size_t)F_IN * F_HID * 2);
    unsigned short* W2t  = (unsigned short*)alloc((size_t)F_HID * F_HID * 2);
    float* hw3 = (float*)alloc((size_t)n * F_OUT * 4);

    const int TB = 256;
    // one memset covers cnt + cursor (adjacent)
    hipMemsetAsync(cnt, 0, cntpad + (size_t)n * 4, stream);

    // prep: count + cast x + castT W1 + castT W2
    int xq = (int)((size_t)n * F_IN / 4);
    int prepmax = e > xq ? e : xq;
    dim3 gp((prepmax + TB - 1) / TB, 4);
    prep_kernel<<<gp, TB, 0, stream>>>(dstp, cnt, e, x, xb, xq, W1, W1t, W2, W2t);

    int nb = (n + TB - 1) / TB;
    scan1_kernel<<<nb, TB, 0, stream>>>(cnt, rowstart, partial, dinv, n);
    scan2_kernel<<<1, TB, 0, stream>>>(partial, nb);
    scan3_kernel<<<nb, TB, 0, stream>>>(rowstart, partial, n, e);
    fill_kernel<<<(e + TB - 1) / TB, TB, 0, stream>>>(srcp, dstp, rowstart, cursor, dinv,
                                                      pack, e);

    int nwave = (n + 3) / 4;
    dim3 gg((n + 63) / 64, F_HID / 64);

    // Layer 1: aggregate x_bf16 (128) -> aggb, MFMA GEMM+bias+relu -> h1 (bf16)
    agg_kernel<F_IN><<<nwave, 256, 0, stream>>>(xb, rowstart, pack, dinv, aggb, n);
    gemm_mfma_kernel<F_IN, true, true><<<gg, 256, 0, stream>>>(aggb, W1t, b1, nullptr, h1b,
                                                               n, F_HID);

    // Layer 2: aggregate h1_bf16 (256) -> aggb, MFMA GEMM+bias+relu -> h2 (bf16)
    agg_kernel<F_HID><<<nwave, 256, 0, stream>>>(h1b, rowstart, pack, dinv, aggb, n);
    gemm_mfma_kernel<F_HID, true, true><<<gg, 256, 0, stream>>>(aggb, W2t, b2, nullptr, h2b,
                                                                n, F_HID);

    // Layer 3: GEMM to 10-dim, aggregate 10-dim + bias + log_softmax
    gemm3_kernel<<<(n + TB - 1) / TB, TB, 0, stream>>>(h2b, W3, hw3, n);
    final_kernel<<<(n + TB - 1) / TB, TB, 0, stream>>>(hw3, rowstart, pack, dinv, b3, out, n);
}